// Round 1
// baseline (237.800 us; speedup 1.0000x reference)
//
#include <hip/hip_runtime.h>
#include <math.h>

#define KPTS 512
#define VOX (64*64*64)
#define NCAND 8192
#define NSEL 1024

typedef unsigned long long u64;
typedef unsigned int u32;

// f32 op-sequence sigmoid with correctly-rounded expf (via double):
// t = rn(exp(-x)); s = 1/(1+t)  -- mimics NumPy f32 semantics.
__device__ __forceinline__ float ref_sigmoid(float x) {
  float t = (float)exp(-(double)x);
  float d = 1.0f + t;
  return 1.0f / d;
}

__global__ void zero_counts(u32* counts) {
  if (threadIdx.x < 4) counts[threadIdx.x] = 0;
}

// One wave per 4x4x4 NMS block. Candidates = all voxels whose sigmoid equals
// the block max (matches sup = where(r==m, r, 0); all sigmoids > 0).
__global__ void nms_cand(const float* __restrict__ k1, const float* __restrict__ k2,
                         u32* __restrict__ counts, u64* __restrict__ cands) {
  int nb = blockIdx.x;          // 0..4095 NMS block
  int inst = blockIdx.y;        // 0..3 : m = inst>>1, b = inst&1
  const float* vol = ((inst >> 1) ? k2 : k1) + (size_t)(inst & 1) * VOX;
  int lane = threadIdx.x;       // 64 voxels per block
  int x = ((nb & 15) << 2) | (lane & 3);
  int y = (((nb >> 4) & 15) << 2) | ((lane >> 2) & 3);
  int z = ((nb >> 8) << 2) | (lane >> 4);
  int addr = (z << 12) | (y << 6) | x;   // z*H*W + y*W + x
  float s = ref_sigmoid(vol[addr]);
  float mx = s;
  #pragma unroll
  for (int o = 32; o; o >>= 1) mx = fmaxf(mx, __shfl_xor(mx, o));
  if (s == mx) {
    u32 pos = atomicAdd(&counts[inst], 1u);
    if (pos < NCAND)
      cands[(size_t)inst * NCAND + pos] =
        ((u64)__float_as_uint(s) << 32) | (u64)(0xFFFFFFFFu - (u32)addr);
  }
}

// Per instance: histogram-prune candidates to the >=512 largest (<~600
// typically), bitonic-sort 1024 by (value desc, index asc), emit top 512.
__global__ void __launch_bounds__(1024) topk_sel(
    const u32* __restrict__ counts, const u64* __restrict__ cands,
    int* __restrict__ pts, float* __restrict__ out) {
  __shared__ u32 hist[256];
  __shared__ u64 sel[NSEL];
  __shared__ u32 selCnt;
  __shared__ int bstar;
  int inst = blockIdx.x, tid = threadIdx.x;
  u32 cnt = counts[inst]; if (cnt > NCAND) cnt = NCAND;
  if (tid < 256) hist[tid] = 0;
  if (tid == 0) selCnt = 0;
  __syncthreads();
  const u64* cb = cands + (size_t)inst * NCAND;
  // 256 value-ordered bins: sigmoid in [0.5,1) -> mantissa bits [22:15]
  for (u32 i = tid; i < cnt; i += 1024) {
    u32 vb = (u32)(cb[i] >> 32);
    int bin = (vb >= 0x3F800000u) ? 255 : ((vb < 0x3F000000u) ? 0 : (int)((vb >> 15) & 0xFF));
    atomicAdd(&hist[bin], 1u);
  }
  __syncthreads();
  if (tid == 0) {
    u32 cum = 0; int b = 255;
    for (; b >= 0; b--) { cum += hist[b]; if (cum >= KPTS) break; }
    bstar = (b < 0) ? 0 : b;
  }
  __syncthreads();
  int B = bstar;
  for (u32 i = tid; i < cnt; i += 1024) {
    u64 key = cb[i];
    u32 vb = (u32)(key >> 32);
    int bin = (vb >= 0x3F800000u) ? 255 : ((vb < 0x3F000000u) ? 0 : (int)((vb >> 15) & 0xFF));
    if (bin >= B) {
      u32 p = atomicAdd(&selCnt, 1u);
      if (p < NSEL) sel[p] = key;
    }
  }
  __syncthreads();
  u32 sc = selCnt; if (sc > NSEL) sc = NSEL;
  for (int i = tid; i < NSEL; i += 1024) if (i >= (int)sc) sel[i] = 0ull;
  __syncthreads();
  // bitonic sort, descending; keys unique (idx distinct) -> deterministic
  for (int k = 2; k <= NSEL; k <<= 1) {
    for (int j = k >> 1; j > 0; j >>= 1) {
      int i = tid, l = tid ^ j;
      if (i < NSEL && l > i) {
        u64 a = sel[i], b2 = sel[l];
        bool desc = ((i & k) == 0);
        if (desc ? (a < b2) : (a > b2)) { sel[i] = b2; sel[l] = a; }
      }
      __syncthreads();
    }
  }
  if (tid < KPTS) {
    u32 idx = ~(u32)(sel[tid]);           // 0xFFFFFFFF - low
    pts[inst * KPTS + tid] = (int)idx;
    int x = idx & 63, y = (idx >> 6) & 63, z = (int)(idx >> 12);
    float gx = ((float)x * 2.0f) / 63.0f - 1.0f;
    float gy = ((float)y * 2.0f) / 63.0f - 1.0f;
    float gz = ((float)z * 2.0f) / 63.0f - 1.0f;
    int m = inst >> 1, b = inst & 1;
    float* g = out + (size_t)m * 3072 + (size_t)(b * KPTS + tid) * 3;
    g[0] = gx; g[1] = gy; g[2] = gz;
  }
}

// One block per (instance, point); lane = channel. Trilinear sample of the
// feature volume (desc) and, on lane 0, the kpt map (logits). Also ||desc||.
__global__ void sample_kernel(const float* __restrict__ k1, const float* __restrict__ k2,
                              const float* __restrict__ f1, const float* __restrict__ f2,
                              const int* __restrict__ pts, float* __restrict__ desc,
                              float* __restrict__ norms, float* __restrict__ out) {
  int bid = blockIdx.x;
  int inst = bid >> 9, kp = bid & 511;
  int m = inst >> 1, b = inst & 1;
  int lane = threadIdx.x;   // channel 0..63
  int idx = pts[inst * KPTS + kp];
  int x = idx & 63, y = (idx >> 6) & 63, z = idx >> 12;
  float gx = ((float)x * 2.0f) / 63.0f - 1.0f;
  float gy = ((float)y * 2.0f) / 63.0f - 1.0f;
  float gz = ((float)z * 2.0f) / 63.0f - 1.0f;
  float ix = ((gx + 1.0f) * 64.0f - 1.0f) * 0.5f;
  float iy = ((gy + 1.0f) * 64.0f - 1.0f) * 0.5f;
  float iz = ((gz + 1.0f) * 64.0f - 1.0f) * 0.5f;
  float x0f = floorf(ix), y0f = floorf(iy), z0f = floorf(iz);
  float fx = ix - x0f, fy = iy - y0f, fz = iz - z0f;
  int x0 = (int)x0f, y0 = (int)y0f, z0 = (int)z0f;
  const float* fv = (m ? f2 : f1) + ((size_t)b * 64 + lane) * VOX;
  float acc = 0.0f;
  #pragma unroll
  for (int dz = 0; dz < 2; dz++)
  #pragma unroll
  for (int dy = 0; dy < 2; dy++)
  #pragma unroll
  for (int dx = 0; dx < 2; dx++) {
    int xi = x0 + dx, yi = y0 + dy, zi = z0 + dz;
    float w = (dx ? fx : 1.0f - fx) * (dy ? fy : 1.0f - fy) * (dz ? fz : 1.0f - fz);
    if (((unsigned)xi < 64u) & ((unsigned)yi < 64u) & ((unsigned)zi < 64u))
      acc = fmaf(fv[(zi << 12) | (yi << 6) | xi], w, acc);
  }
  desc[((size_t)inst * 64 + lane) * KPTS + kp] = acc;
  float ss = acc * acc;
  #pragma unroll
  for (int o = 32; o; o >>= 1) ss += __shfl_xor(ss, o);
  if (lane == 0) {
    norms[inst * KPTS + kp] = sqrtf(ss);
    const float* kv = (m ? k2 : k1) + (size_t)b * VOX;
    float lac = 0.0f;
    #pragma unroll
    for (int dz = 0; dz < 2; dz++)
    for (int dy = 0; dy < 2; dy++)
    for (int dx = 0; dx < 2; dx++) {
      int xi = x0 + dx, yi = y0 + dy, zi = z0 + dz;
      float w = (dx ? fx : 1.0f - fx) * (dy ? fy : 1.0f - fy) * (dz ? fz : 1.0f - fz);
      if (((unsigned)xi < 64u) & ((unsigned)yi < 64u) & ((unsigned)zi < 64u))
        lac = fmaf(kv[(zi << 12) | (yi << 6) | xi], w, lac);
    }
    out[6144 + m * 1024 + b * KPTS + kp] = lac;
  }
}

// 32x32 (i,j) tile per block; scores (2 weighted dot-products over C=64) and
// desc_norm = n1_i * |1/(1e-6+n1_i) - 1/(1e-6+n2_j)| (both numerators are d1
// in the reference).
__global__ void __launch_bounds__(256) matcher(const float* __restrict__ desc,
                                               const float* __restrict__ norms,
                                               const float* __restrict__ fc_w,
                                               const float* __restrict__ fc_b,
                                               float* __restrict__ out) {
  int bid = blockIdx.x;
  int b = bid >> 8, ti = (bid >> 4) & 15, tj = bid & 15;
  __shared__ float d1t[64][32], d2t[64][32];
  __shared__ float n1s[32], n2s[32], w0s[64], w1s[64];
  int tid = threadIdx.x;
  const float* d1 = desc + (size_t)(b) * 64 * KPTS;        // inst = b (map1)
  const float* d2 = desc + (size_t)(2 + b) * 64 * KPTS;    // inst = 2+b (map2)
  int i0 = ti * 32, j0 = tj * 32;
  for (int t = tid; t < 64 * 32; t += 256) {
    int c = t >> 5, ii = t & 31;
    d1t[c][ii] = d1[c * KPTS + i0 + ii];
    d2t[c][ii] = d2[c * KPTS + j0 + ii];
  }
  if (tid < 32) n1s[tid] = norms[b * KPTS + i0 + tid];
  else if (tid < 64) n2s[tid - 32] = norms[(2 + b) * KPTS + j0 + (tid - 32)];
  else if (tid < 128) w0s[tid - 64] = fc_w[tid - 64];
  else if (tid < 192) w1s[tid - 128] = fc_w[64 + (tid - 128)];
  __syncthreads();
  float bb0 = fc_b[0], bb1 = fc_b[1];
  int j = tid & 31, r0 = tid >> 5;
  for (int r = 0; r < 4; r++) {
    int i = r0 + r * 8;
    float a0 = 0.0f, a1 = 0.0f;
    for (int c = 0; c < 64; c++) {
      float p = d1t[c][i] * d2t[c][j];
      a0 = fmaf(p, w0s[c], a0);
      a1 = fmaf(p, w1s[c], a1);
    }
    int gi = i0 + i, gj = j0 + j;
    size_t row = ((size_t)(b * KPTS + gi)) * KPTS + gj;
    out[8192 + row * 2 + 0] = a0 + bb0;
    out[8192 + row * 2 + 1] = a1 + bb1;
    float n1 = n1s[i], n2 = n2s[j];
    out[1056768 + row] = n1 * fabsf(1.0f / (1e-6f + n1) - 1.0f / (1e-6f + n2));
  }
}

extern "C" void kernel_launch(void* const* d_in, const int* in_sizes, int n_in,
                              void* d_out, int out_size, void* d_ws, size_t ws_size,
                              hipStream_t stream) {
  const float* k1 = (const float*)d_in[0];
  const float* k2 = (const float*)d_in[1];
  const float* f1 = (const float*)d_in[2];
  const float* f2 = (const float*)d_in[3];
  const float* fw = (const float*)d_in[4];
  const float* fb = (const float*)d_in[5];
  float* out = (float*)d_out;
  char* ws = (char*)d_ws;
  // ws layout: counts(64B) | cands(4*8192*8B) | pts(4*512*4B) | norms(4*512*4B) | desc(4*64*512*4B)
  u32* counts = (u32*)ws;
  u64* cands  = (u64*)(ws + 64);
  int* pts    = (int*)(ws + 64 + 262144);
  float* norms = (float*)(ws + 64 + 262144 + 8192);
  float* desc  = (float*)(ws + 64 + 262144 + 8192 + 8192);

  hipLaunchKernelGGL(zero_counts, dim3(1), dim3(64), 0, stream, counts);
  hipLaunchKernelGGL(nms_cand, dim3(4096, 4), dim3(64), 0, stream, k1, k2, counts, cands);
  hipLaunchKernelGGL(topk_sel, dim3(4), dim3(1024), 0, stream, counts, cands, pts, out);
  hipLaunchKernelGGL(sample_kernel, dim3(2048), dim3(64), 0, stream, k1, k2, f1, f2, pts, desc, norms, out);
  hipLaunchKernelGGL(matcher, dim3(512), dim3(256), 0, stream, desc, norms, fw, fb, out);
}

// Round 2
// 55.189 us; speedup vs baseline: 4.3089x; 4.3089x over previous
//
#include <hip/hip_runtime.h>
#include <math.h>

#define KPTS 512
#define VOX (64*64*64)
#define NBLK 4096          // 16x16x16 NMS blocks per instance
#define NOVF 1024          // overflow (tie) slots per instance
#define NCAND (NBLK + NOVF)
#define NSEL 1024

typedef unsigned long long u64;
typedef unsigned int u32;

// f32 op-sequence sigmoid with correctly-rounded expf (via double):
// t = rn(exp(-x)); s = 1/(1+t)  -- mimics NumPy f32 semantics.
__device__ __forceinline__ float ref_sigmoid(float x) {
  float t = (float)exp(-(double)x);
  float d = 1.0f + t;
  return 1.0f / d;
}

__global__ void zero_counts(u32* counts) {
  if (threadIdx.x < 4) counts[threadIdx.x] = 0;
}

// One wave per 4x4x4 NMS block. Deterministic slot per block for the first
// (lowest-address) winner; rare tied co-winners go to a per-instance overflow
// list (atomic is effectively uncontended). Every slot is written every call.
__global__ void nms_cand(const float* __restrict__ k1, const float* __restrict__ k2,
                         u32* __restrict__ ovf_counts, u64* __restrict__ cands) {
  int nb = blockIdx.x;          // 0..4095 NMS block
  int inst = blockIdx.y;        // 0..3 : m = inst>>1, b = inst&1
  const float* vol = ((inst >> 1) ? k2 : k1) + (size_t)(inst & 1) * VOX;
  int lane = threadIdx.x;       // 64 voxels per block
  int x = ((nb & 15) << 2) | (lane & 3);
  int y = (((nb >> 4) & 15) << 2) | ((lane >> 2) & 3);
  int z = ((nb >> 8) << 2) | (lane >> 4);
  int addr = (z << 12) | (y << 6) | x;   // z*H*W + y*W + x
  float s = ref_sigmoid(vol[addr]);
  float mx = s;
  #pragma unroll
  for (int o = 32; o; o >>= 1) mx = fmaxf(mx, __shfl_xor(mx, o));
  bool win = (s == mx);
  u64 wmask = __ballot(win);
  int firstLane = __ffsll(wmask) - 1;    // lowest lane index => lowest addr
  u64 key = ((u64)__float_as_uint(s) << 32) | (u64)(0xFFFFFFFFu - (u32)addr);
  u64* cb = cands + (size_t)inst * NCAND;
  if (win) {
    if (lane == firstLane) {
      cb[nb] = key;                      // fixed slot, no atomic
    } else {                             // tie within block: rare
      u32 p = atomicAdd(&ovf_counts[inst], 1u);
      if (p < NOVF) cb[NBLK + p] = key;
    }
  }
}

// Per instance: histogram-prune candidates to the >=512 largest (<~700
// typically), bitonic-sort 1024 by (value desc, index asc), emit top 512.
__global__ void __launch_bounds__(1024) topk_sel(
    const u32* __restrict__ ovf_counts, const u64* __restrict__ cands,
    int* __restrict__ pts, float* __restrict__ out) {
  __shared__ u32 hist[256];
  __shared__ u64 sel[NSEL];
  __shared__ u32 selCnt;
  __shared__ int bstar;
  int inst = blockIdx.x, tid = threadIdx.x;
  u32 ov = ovf_counts[inst]; if (ov > NOVF) ov = NOVF;
  u32 cnt = NBLK + ov;
  if (tid < 256) hist[tid] = 0;
  if (tid == 0) selCnt = 0;
  __syncthreads();
  const u64* cb = cands + (size_t)inst * NCAND;
  // 256 value-ordered bins: sigmoid in [0.5,1) -> mantissa bits [22:15]
  for (u32 i = tid; i < cnt; i += 1024) {
    u32 vb = (u32)(cb[i] >> 32);
    int bin = (vb >= 0x3F800000u) ? 255 : ((vb < 0x3F000000u) ? 0 : (int)((vb >> 15) & 0xFF));
    atomicAdd(&hist[bin], 1u);
  }
  __syncthreads();
  if (tid == 0) {
    u32 cum = 0; int b = 255;
    for (; b >= 0; b--) { cum += hist[b]; if (cum >= KPTS) break; }
    bstar = (b < 0) ? 0 : b;
  }
  __syncthreads();
  int B = bstar;
  for (u32 i = tid; i < cnt; i += 1024) {
    u64 key = cb[i];
    u32 vb = (u32)(key >> 32);
    int bin = (vb >= 0x3F800000u) ? 255 : ((vb < 0x3F000000u) ? 0 : (int)((vb >> 15) & 0xFF));
    if (bin >= B) {
      u32 p = atomicAdd(&selCnt, 1u);
      if (p < NSEL) sel[p] = key;
    }
  }
  __syncthreads();
  u32 sc = selCnt; if (sc > NSEL) sc = NSEL;
  for (int i = tid; i < NSEL; i += 1024) if (i >= (int)sc) sel[i] = 0ull;
  __syncthreads();
  // bitonic sort, descending; keys unique (idx distinct) -> deterministic
  for (int k = 2; k <= NSEL; k <<= 1) {
    for (int j = k >> 1; j > 0; j >>= 1) {
      int i = tid, l = tid ^ j;
      if (i < NSEL && l > i) {
        u64 a = sel[i], b2 = sel[l];
        bool desc = ((i & k) == 0);
        if (desc ? (a < b2) : (a > b2)) { sel[i] = b2; sel[l] = a; }
      }
      __syncthreads();
    }
  }
  if (tid < KPTS) {
    u32 idx = ~(u32)(sel[tid]);           // 0xFFFFFFFF - low
    pts[inst * KPTS + tid] = (int)idx;
    int x = idx & 63, y = (idx >> 6) & 63, z = (int)(idx >> 12);
    float gx = ((float)x * 2.0f) / 63.0f - 1.0f;
    float gy = ((float)y * 2.0f) / 63.0f - 1.0f;
    float gz = ((float)z * 2.0f) / 63.0f - 1.0f;
    int m = inst >> 1, b = inst & 1;
    float* g = out + (size_t)m * 3072 + (size_t)(b * KPTS + tid) * 3;
    g[0] = gx; g[1] = gy; g[2] = gz;
  }
}

// One block per (instance, point); lane = channel. Trilinear sample of the
// feature volume (desc) and, on lane 0, the kpt map (logits). Also ||desc||.
__global__ void sample_kernel(const float* __restrict__ k1, const float* __restrict__ k2,
                              const float* __restrict__ f1, const float* __restrict__ f2,
                              const int* __restrict__ pts, float* __restrict__ desc,
                              float* __restrict__ norms, float* __restrict__ out) {
  int bid = blockIdx.x;
  int inst = bid >> 9, kp = bid & 511;
  int m = inst >> 1, b = inst & 1;
  int lane = threadIdx.x;   // channel 0..63
  int idx = pts[inst * KPTS + kp];
  int x = idx & 63, y = (idx >> 6) & 63, z = idx >> 12;
  float gx = ((float)x * 2.0f) / 63.0f - 1.0f;
  float gy = ((float)y * 2.0f) / 63.0f - 1.0f;
  float gz = ((float)z * 2.0f) / 63.0f - 1.0f;
  float ix = ((gx + 1.0f) * 64.0f - 1.0f) * 0.5f;
  float iy = ((gy + 1.0f) * 64.0f - 1.0f) * 0.5f;
  float iz = ((gz + 1.0f) * 64.0f - 1.0f) * 0.5f;
  float x0f = floorf(ix), y0f = floorf(iy), z0f = floorf(iz);
  float fx = ix - x0f, fy = iy - y0f, fz = iz - z0f;
  int x0 = (int)x0f, y0 = (int)y0f, z0 = (int)z0f;
  const float* fv = (m ? f2 : f1) + ((size_t)b * 64 + lane) * VOX;
  float acc = 0.0f;
  #pragma unroll
  for (int dz = 0; dz < 2; dz++)
  #pragma unroll
  for (int dy = 0; dy < 2; dy++)
  #pragma unroll
  for (int dx = 0; dx < 2; dx++) {
    int xi = x0 + dx, yi = y0 + dy, zi = z0 + dz;
    float w = (dx ? fx : 1.0f - fx) * (dy ? fy : 1.0f - fy) * (dz ? fz : 1.0f - fz);
    if (((unsigned)xi < 64u) & ((unsigned)yi < 64u) & ((unsigned)zi < 64u))
      acc = fmaf(fv[(zi << 12) | (yi << 6) | xi], w, acc);
  }
  desc[((size_t)inst * 64 + lane) * KPTS + kp] = acc;
  float ss = acc * acc;
  #pragma unroll
  for (int o = 32; o; o >>= 1) ss += __shfl_xor(ss, o);
  if (lane == 0) {
    norms[inst * KPTS + kp] = sqrtf(ss);
    const float* kv = (m ? k2 : k1) + (size_t)b * VOX;
    float lac = 0.0f;
    #pragma unroll
    for (int dz = 0; dz < 2; dz++)
    for (int dy = 0; dy < 2; dy++)
    for (int dx = 0; dx < 2; dx++) {
      int xi = x0 + dx, yi = y0 + dy, zi = z0 + dz;
      float w = (dx ? fx : 1.0f - fx) * (dy ? fy : 1.0f - fy) * (dz ? fz : 1.0f - fz);
      if (((unsigned)xi < 64u) & ((unsigned)yi < 64u) & ((unsigned)zi < 64u))
        lac = fmaf(kv[(zi << 12) | (yi << 6) | xi], w, lac);
    }
    out[6144 + m * 1024 + b * KPTS + kp] = lac;
  }
}

// 32x32 (i,j) tile per block; scores (2 weighted dot-products over C=64) and
// desc_norm = n1_i * |1/(1e-6+n1_i) - 1/(1e-6+n2_j)| (both numerators are d1
// in the reference).
__global__ void __launch_bounds__(256) matcher(const float* __restrict__ desc,
                                               const float* __restrict__ norms,
                                               const float* __restrict__ fc_w,
                                               const float* __restrict__ fc_b,
                                               float* __restrict__ out) {
  int bid = blockIdx.x;
  int b = bid >> 8, ti = (bid >> 4) & 15, tj = bid & 15;
  __shared__ float d1t[64][32], d2t[64][32];
  __shared__ float n1s[32], n2s[32], w0s[64], w1s[64];
  int tid = threadIdx.x;
  const float* d1 = desc + (size_t)(b) * 64 * KPTS;        // inst = b (map1)
  const float* d2 = desc + (size_t)(2 + b) * 64 * KPTS;    // inst = 2+b (map2)
  int i0 = ti * 32, j0 = tj * 32;
  for (int t = tid; t < 64 * 32; t += 256) {
    int c = t >> 5, ii = t & 31;
    d1t[c][ii] = d1[c * KPTS + i0 + ii];
    d2t[c][ii] = d2[c * KPTS + j0 + ii];
  }
  if (tid < 32) n1s[tid] = norms[b * KPTS + i0 + tid];
  else if (tid < 64) n2s[tid - 32] = norms[(2 + b) * KPTS + j0 + (tid - 32)];
  else if (tid < 128) w0s[tid - 64] = fc_w[tid - 64];
  else if (tid < 192) w1s[tid - 128] = fc_w[64 + (tid - 128)];
  __syncthreads();
  float bb0 = fc_b[0], bb1 = fc_b[1];
  int j = tid & 31, r0 = tid >> 5;
  for (int r = 0; r < 4; r++) {
    int i = r0 + r * 8;
    float a0 = 0.0f, a1 = 0.0f;
    for (int c = 0; c < 64; c++) {
      float p = d1t[c][i] * d2t[c][j];
      a0 = fmaf(p, w0s[c], a0);
      a1 = fmaf(p, w1s[c], a1);
    }
    int gi = i0 + i, gj = j0 + j;
    size_t row = ((size_t)(b * KPTS + gi)) * KPTS + gj;
    out[8192 + row * 2 + 0] = a0 + bb0;
    out[8192 + row * 2 + 1] = a1 + bb1;
    float n1 = n1s[i], n2 = n2s[j];
    out[1056768 + row] = n1 * fabsf(1.0f / (1e-6f + n1) - 1.0f / (1e-6f + n2));
  }
}

extern "C" void kernel_launch(void* const* d_in, const int* in_sizes, int n_in,
                              void* d_out, int out_size, void* d_ws, size_t ws_size,
                              hipStream_t stream) {
  const float* k1 = (const float*)d_in[0];
  const float* k2 = (const float*)d_in[1];
  const float* f1 = (const float*)d_in[2];
  const float* f2 = (const float*)d_in[3];
  const float* fw = (const float*)d_in[4];
  const float* fb = (const float*)d_in[5];
  float* out = (float*)d_out;
  char* ws = (char*)d_ws;
  // ws layout: ovf_counts(64B) | cands(4*5120*8B) | pts(4*512*4B) | norms(4*512*4B) | desc(4*64*512*4B)
  u32* counts = (u32*)ws;
  u64* cands  = (u64*)(ws + 64);
  int* pts    = (int*)(ws + 64 + 4 * NCAND * 8);
  float* norms = (float*)(ws + 64 + 4 * NCAND * 8 + 8192);
  float* desc  = (float*)(ws + 64 + 4 * NCAND * 8 + 8192 + 8192);

  hipLaunchKernelGGL(zero_counts, dim3(1), dim3(64), 0, stream, counts);
  hipLaunchKernelGGL(nms_cand, dim3(NBLK, 4), dim3(64), 0, stream, k1, k2, counts, cands);
  hipLaunchKernelGGL(topk_sel, dim3(4), dim3(1024), 0, stream, counts, cands, pts, out);
  hipLaunchKernelGGL(sample_kernel, dim3(2048), dim3(64), 0, stream, k1, k2, f1, f2, pts, desc, norms, out);
  hipLaunchKernelGGL(matcher, dim3(512), dim3(256), 0, stream, desc, norms, fw, fb, out);
}